// Round 1
// baseline (1092.630 us; speedup 1.0000x reference)
//
#include <hip/hip_runtime.h>

constexpr int NN = 50000;     // nodes
constexpr int NE = 800000;    // edges
constexpr float SLOPE_A = 0.2f;   // attention leaky_relu
constexpr float SLOPE_R = 0.01f;  // activation leaky_relu

typedef __attribute__((ext_vector_type(8))) short bf16x8;
typedef __attribute__((ext_vector_type(4))) float f32x4;

__device__ __forceinline__ unsigned short f2bf(float f) {
    union { float f; unsigned u; } v; v.f = f;
    unsigned u = v.u;
    unsigned r = u + 0x7fffu + ((u >> 16) & 1u);  // round-to-nearest-even
    return (unsigned short)(r >> 16);
}

// ---------------- CSR build ----------------
__global__ void k_hist(const int* __restrict__ dst, int* __restrict__ cnt) {
    int i = blockIdx.x * 256 + threadIdx.x;
    if (i < NE) atomicAdd(&cnt[dst[i]], 1);
}

__global__ void k_scan(int* __restrict__ cc, int* __restrict__ rowptr) {
    // one block, 1024 threads; cc holds counts on entry, cursor offsets on exit
    __shared__ int part[1024];
    int t = threadIdx.x;
    const int CHK = 49;  // 1024*49 = 50176 >= 50000
    int base = t * CHK;
    int s = 0;
    for (int i = 0; i < CHK; i++) {
        int idx = base + i;
        if (idx < NN) s += cc[idx];
    }
    part[t] = s;
    __syncthreads();
    for (int off = 1; off < 1024; off <<= 1) {
        int v = (t >= off) ? part[t - off] : 0;
        __syncthreads();
        part[t] += v;
        __syncthreads();
    }
    int running = part[t] - s;  // exclusive prefix
    for (int i = 0; i < CHK; i++) {
        int idx = base + i;
        if (idx < NN) {
            int c = cc[idx];
            rowptr[idx] = running;
            cc[idx] = running;   // becomes scatter cursor
            running += c;
        }
    }
    if (t == 1023) rowptr[NN] = running;
}

__global__ void k_scatter(const int* __restrict__ src, const int* __restrict__ dst,
                          int* __restrict__ cursor, int* __restrict__ ssrc) {
    int i = blockIdx.x * 256 + threadIdx.x;
    if (i < NE) {
        int d = dst[i];
        int pos = atomicAdd(&cursor[d], 1);
        ssrc[pos] = src[i];
    }
}

// ---------------- W -> bf16 transposed (Wt[j][k] = W[k][j]) ----------------
__global__ void k_prepw(const float* __restrict__ W1, const float* __restrict__ W2,
                        const float* __restrict__ W3, unsigned short* __restrict__ Wt) {
    int b = blockIdx.x;          // 768 = 3 layers * 256 k-rows
    int L = b >> 8, k = b & 255;
    const float* W = (L == 0) ? W1 : ((L == 1) ? W2 : W3);
    int j = threadIdx.x;
    Wt[L * 65536 + j * 256 + k] = f2bf(W[k * 256 + j]);
}

// ---------------- GEMM: feat = BN(A) @ W  (bf16 MFMA, fp32 acc) ----------------
// block: 256 thr = 4 waves; tile 64 rows x 256 cols; wave w owns cols [64w,64w+64)
__launch_bounds__(256, 2)
__global__ void k_gemm(const float* __restrict__ A, const unsigned short* __restrict__ Wt,
                       const float* __restrict__ bnscale, const float* __restrict__ bnshift,
                       int use_bn, float* __restrict__ feat) {
    constexpr int AP = 264;  // A lds pitch in bf16 elems (528B = 33*16B, row starts 16B-aligned)
    constexpr int BP = 40;   // B lds pitch (80B)
    __shared__ __align__(16) unsigned short Alds[64 * AP];
    __shared__ __align__(16) unsigned short Blds[256 * BP];
    const int tid = threadIdx.x;
    const int rowbase = blockIdx.x * 64;

    // stage A: 64 rows x K=256, fp32 -> (BN) -> bf16
    {
        int r = tid >> 6;       // 0..3 within group of 4 rows
        int c4 = tid & 63;      // float4 index along K
        for (int it = 0; it < 16; it++) {
            int rr = it * 4 + r;
            int gr = rowbase + rr;
            float4 v = make_float4(0.f, 0.f, 0.f, 0.f);
            if (gr < NN) v = *(const float4*)(A + (size_t)gr * 256 + c4 * 4);
            if (use_bn) {
                float4 sc = *(const float4*)(bnscale + c4 * 4);
                float4 sh = *(const float4*)(bnshift + c4 * 4);
                v.x = v.x * sc.x + sh.x;
                v.y = v.y * sc.y + sh.y;
                v.z = v.z * sc.z + sh.z;
                v.w = v.w * sc.w + sh.w;
            }
            ushort4 pv;
            pv.x = f2bf(v.x); pv.y = f2bf(v.y); pv.z = f2bf(v.z); pv.w = f2bf(v.w);
            *(ushort4*)(&Alds[rr * AP + c4 * 4]) = pv;
        }
    }

    f32x4 acc[4][4];
    for (int i = 0; i < 4; i++)
        for (int j = 0; j < 4; j++)
            acc[i][j] = (f32x4){0.f, 0.f, 0.f, 0.f};

    const int lane = tid & 63, w = tid >> 6;
    const int mm = lane & 15, q = lane >> 4;

    for (int kc = 0; kc < 8; kc++) {
        __syncthreads();
        // stage B chunk: Blds[n][kk] = Wt[n][kc*32+kk], 256 x 32 bf16
        for (int i = 0; i < 4; i++) {
            int idx = i * 256 + tid;
            int j = idx >> 2, part = idx & 3;
            uint4 vv = *(const uint4*)(Wt + j * 256 + kc * 32 + part * 8);
            *(uint4*)(&Blds[j * BP + part * 8]) = vv;
        }
        __syncthreads();
        bf16x8 a[4], b[4];
        for (int i = 0; i < 4; i++)
            a[i] = *(const bf16x8*)(&Alds[(16 * i + mm) * AP + kc * 32 + q * 8]);
        for (int j = 0; j < 4; j++)
            b[j] = *(const bf16x8*)(&Blds[(64 * w + 16 * j + mm) * BP + q * 8]);
        for (int i = 0; i < 4; i++)
            for (int j = 0; j < 4; j++)
                acc[i][j] = __builtin_amdgcn_mfma_f32_16x16x32_bf16(a[i], b[j], acc[i][j], 0, 0, 0);
    }

    // epilogue: C/D layout col=lane&15, row=(lane>>4)*4+reg  [m89-verified]
    for (int i = 0; i < 4; i++) {
        int gr0 = rowbase + 16 * i + q * 4;
        for (int j = 0; j < 4; j++) {
            int gc = 64 * w + 16 * j + mm;
            for (int r = 0; r < 4; r++) {
                int gr = gr0 + r;
                if (gr < NN) feat[(size_t)gr * 256 + gc] = acc[i][j][r];
            }
        }
    }
}

// ---------------- el/er = sum(feat*al/ar over D) ----------------
__global__ void k_elr(const float* __restrict__ feat, const float* __restrict__ al,
                      const float* __restrict__ ar, float* __restrict__ el,
                      float* __restrict__ er) {
    int n = blockIdx.x * 4 + (threadIdx.x >> 6);
    int l = threadIdx.x & 63;
    int h = l >> 4, g = l & 15;
    float4 f = *(const float4*)(feat + (size_t)n * 256 + l * 4);
    float4 a = *(const float4*)(al + h * 64 + g * 4);
    float4 r = *(const float4*)(ar + h * 64 + g * 4);
    float se = f.x * a.x + f.y * a.y + f.z * a.z + f.w * a.w;
    float sr = f.x * r.x + f.y * r.y + f.z * r.z + f.w * r.w;
    for (int off = 1; off < 16; off <<= 1) {
        se += __shfl_xor(se, off, 64);
        sr += __shfl_xor(sr, off, 64);
    }
    if (g == 0) {
        el[n * 4 + h] = se;
        er[n * 4 + h] = sr;
    }
}

// ---------------- per-dst online softmax + weighted aggregation ----------------
// one wave per destination node; lane l owns channels [4l, 4l+4); head h = l>>4
__launch_bounds__(256)
__global__ void k_agg(const float* __restrict__ feat, const float* __restrict__ el,
                      const float* __restrict__ er, const int* __restrict__ rowptr,
                      const int* __restrict__ ssrc, const float* __restrict__ resid,
                      const float* __restrict__ bnscale, const float* __restrict__ bnshift,
                      int use_bn, const float* __restrict__ bias, int act,
                      float* __restrict__ out, int final_mean) {
    int n = blockIdx.x * 4 + (threadIdx.x >> 6);
    int l = threadIdx.x & 63;
    int h = l >> 4;
    int beg = rowptr[n], end = rowptr[n + 1];
    float erh = er[n * 4 + h];

    // pass 1: online max + denom
    float m = -1e30f, d = 0.f;
    for (int e = beg; e < end; e++) {
        int s = ssrc[e];
        float sc = el[s * 4 + h] + erh;
        sc = (sc > 0.f) ? sc : SLOPE_A * sc;
        float mn = fmaxf(m, sc);
        d = d * __expf(m - mn) + __expf(sc - mn);
        m = mn;
    }
    float invd = 1.f / fmaxf(d, 1e-9f);

    // pass 2: weighted accumulate
    float4 acc = make_float4(0.f, 0.f, 0.f, 0.f);
    for (int e = beg; e < end; e++) {
        int s = ssrc[e];
        float sc = el[s * 4 + h] + erh;
        sc = (sc > 0.f) ? sc : SLOPE_A * sc;
        float wgt = __expf(sc - m) * invd;
        float4 f = *(const float4*)(feat + (size_t)s * 256 + l * 4);
        acc.x += f.x * wgt; acc.y += f.y * wgt; acc.z += f.z * wgt; acc.w += f.w * wgt;
    }

    // residual (+BN) + bias
    float4 r = *(const float4*)(resid + (size_t)n * 256 + l * 4);
    if (use_bn) {
        float4 sc4 = *(const float4*)(bnscale + l * 4);
        float4 sh4 = *(const float4*)(bnshift + l * 4);
        r.x = r.x * sc4.x + sh4.x;
        r.y = r.y * sc4.y + sh4.y;
        r.z = r.z * sc4.z + sh4.z;
        r.w = r.w * sc4.w + sh4.w;
    }
    float4 bb = *(const float4*)(bias + l * 4);
    acc.x += r.x + bb.x; acc.y += r.y + bb.y;
    acc.z += r.z + bb.z; acc.w += r.w + bb.w;
    if (act) {
        acc.x = (acc.x > 0.f) ? acc.x : SLOPE_R * acc.x;
        acc.y = (acc.y > 0.f) ? acc.y : SLOPE_R * acc.y;
        acc.z = (acc.z > 0.f) ? acc.z : SLOPE_R * acc.z;
        acc.w = (acc.w > 0.f) ? acc.w : SLOPE_R * acc.w;
    }

    if (!final_mean) {
        *(float4*)(out + (size_t)n * 256 + l * 4) = acc;
    } else {
        // mean over heads: combine lanes l, l^16, l^32, l^48
        acc.x += __shfl_xor(acc.x, 16, 64); acc.x += __shfl_xor(acc.x, 32, 64);
        acc.y += __shfl_xor(acc.y, 16, 64); acc.y += __shfl_xor(acc.y, 32, 64);
        acc.z += __shfl_xor(acc.z, 16, 64); acc.z += __shfl_xor(acc.z, 32, 64);
        acc.w += __shfl_xor(acc.w, 16, 64); acc.w += __shfl_xor(acc.w, 32, 64);
        if (l < 16) {
            acc.x *= 0.25f; acc.y *= 0.25f; acc.z *= 0.25f; acc.w *= 0.25f;
            *(float4*)(out + (size_t)n * 64 + l * 4) = acc;
        }
    }
}

// ---------------- BatchNorm stats ----------------
__global__ void k_bnstats(const float* __restrict__ hh, float* __restrict__ sums) {
    int t = threadIdx.x;
    int b = blockIdx.x;
    int r0 = b * 196, r1 = min(r0 + 196, NN);
    float s = 0.f, s2 = 0.f;
    for (int r = r0; r < r1; r++) {
        float v = hh[(size_t)r * 256 + t];
        s += v; s2 += v * v;
    }
    atomicAdd(&sums[t], s);
    atomicAdd(&sums[256 + t], s2);
}

__global__ void k_bnfinal(const float* __restrict__ sums, const float* __restrict__ g,
                          const float* __restrict__ be, float* __restrict__ scale,
                          float* __restrict__ shift) {
    int t = threadIdx.x;
    float mu = sums[t] * (1.f / NN);
    float var = sums[256 + t] * (1.f / NN) - mu * mu;
    float rs = rsqrtf(var + 1e-5f);
    float sc = rs * g[t];
    scale[t] = sc;
    shift[t] = be[t] - mu * sc;
}

// ---------------- launcher ----------------
extern "C" void kernel_launch(void* const* d_in, const int* in_sizes, int n_in,
                              void* d_out, int out_size, void* d_ws, size_t ws_size,
                              hipStream_t stream) {
    const float* x   = (const float*)d_in[0];
    const int* src   = (const int*)d_in[1];
    const int* dst   = (const int*)d_in[2];
    const float* W1  = (const float*)d_in[3];
    const float* al1 = (const float*)d_in[4];
    const float* ar1 = (const float*)d_in[5];
    const float* b1  = (const float*)d_in[6];
    const float* W2  = (const float*)d_in[7];
    const float* al2 = (const float*)d_in[8];
    const float* ar2 = (const float*)d_in[9];
    const float* b2  = (const float*)d_in[10];
    const float* W3  = (const float*)d_in[11];
    const float* al3 = (const float*)d_in[12];
    const float* ar3 = (const float*)d_in[13];
    const float* b3  = (const float*)d_in[14];
    const float* g1  = (const float*)d_in[15];
    const float* be1 = (const float*)d_in[16];
    const float* g2  = (const float*)d_in[17];
    const float* be2 = (const float*)d_in[18];
    float* out = (float*)d_out;

    char* ws = (char*)d_ws;
    size_t off = 0;
    auto alloc = [&](size_t bytes) {
        void* p = ws + off;
        off += (bytes + 255) & ~(size_t)255;
        return p;
    };
    int* rowptr = (int*)alloc((NN + 1) * sizeof(int));
    int* cursor = (int*)alloc(NN * sizeof(int));
    int* ssrc   = (int*)alloc(NE * sizeof(int));
    float* feat = (float*)alloc((size_t)NN * 256 * sizeof(float));
    float* hbuf = (float*)alloc((size_t)NN * 256 * sizeof(float));
    float* el   = (float*)alloc((size_t)NN * 4 * sizeof(float));
    float* er   = (float*)alloc((size_t)NN * 4 * sizeof(float));
    unsigned short* Wt = (unsigned short*)alloc(3 * 65536 * sizeof(unsigned short));
    float* bnsums  = (float*)alloc(512 * sizeof(float));
    float* bnscale = (float*)alloc(256 * sizeof(float));
    float* bnshift = (float*)alloc(256 * sizeof(float));

    // CSR build (graph identical for all layers)
    hipMemsetAsync(cursor, 0, NN * sizeof(int), stream);
    k_hist<<<(NE + 255) / 256, 256, 0, stream>>>(dst, cursor);
    k_scan<<<1, 1024, 0, stream>>>(cursor, rowptr);
    k_scatter<<<(NE + 255) / 256, 256, 0, stream>>>(src, dst, cursor, ssrc);
    k_prepw<<<768, 256, 0, stream>>>(W1, W2, W3, Wt);

    const int GB = (NN + 63) / 64;  // 782
    const int NB = NN / 4;          // 12500

    // ---- layer 1 ----
    k_gemm<<<GB, 256, 0, stream>>>(x, Wt, nullptr, nullptr, 0, feat);
    k_elr<<<NB, 256, 0, stream>>>(feat, al1, ar1, el, er);
    k_agg<<<NB, 256, 0, stream>>>(feat, el, er, rowptr, ssrc, x,
                                  nullptr, nullptr, 0, b1, 1, hbuf, 0);
    hipMemsetAsync(bnsums, 0, 512 * sizeof(float), stream);
    k_bnstats<<<256, 256, 0, stream>>>(hbuf, bnsums);
    k_bnfinal<<<1, 256, 0, stream>>>(bnsums, g1, be1, bnscale, bnshift);

    // ---- layer 2 ----
    k_gemm<<<GB, 256, 0, stream>>>(hbuf, Wt + 65536, bnscale, bnshift, 1, feat);
    k_elr<<<NB, 256, 0, stream>>>(feat, al2, ar2, el, er);
    k_agg<<<NB, 256, 0, stream>>>(feat, el, er, rowptr, ssrc, hbuf,
                                  bnscale, bnshift, 1, b2, 1, hbuf, 0);
    hipMemsetAsync(bnsums, 0, 512 * sizeof(float), stream);
    k_bnstats<<<256, 256, 0, stream>>>(hbuf, bnsums);
    k_bnfinal<<<1, 256, 0, stream>>>(bnsums, g2, be2, bnscale, bnshift);

    // ---- layer 3 ----
    k_gemm<<<GB, 256, 0, stream>>>(hbuf, Wt + 131072, bnscale, bnshift, 1, feat);
    k_elr<<<NB, 256, 0, stream>>>(feat, al3, ar3, el, er);
    k_agg<<<NB, 256, 0, stream>>>(feat, el, er, rowptr, ssrc, hbuf,
                                  bnscale, bnshift, 1, b3, 0, out, 1);
}

// Round 2
// 957.561 us; speedup vs baseline: 1.1411x; 1.1411x over previous
//
#include <hip/hip_runtime.h>

constexpr int NN = 50000;     // nodes
constexpr int NE = 800000;    // edges
constexpr float SLOPE_A = 0.2f;   // attention leaky_relu
constexpr float SLOPE_R = 0.01f;  // activation leaky_relu

typedef __attribute__((ext_vector_type(8))) short bf16x8;
typedef __attribute__((ext_vector_type(4))) float f32x4;

__device__ __forceinline__ unsigned short f2bf(float f) {
    union { float f; unsigned u; } v; v.f = f;
    unsigned u = v.u;
    unsigned r = u + 0x7fffu + ((u >> 16) & 1u);  // round-to-nearest-even
    return (unsigned short)(r >> 16);
}
__device__ __forceinline__ float bf2f(unsigned short s) {
    union { unsigned u; float f; } v; v.u = ((unsigned)s) << 16;
    return v.f;
}

// ---------------- CSR build ----------------
__global__ void k_hist(const int* __restrict__ dst, int* __restrict__ cnt) {
    int i = blockIdx.x * 256 + threadIdx.x;
    if (i < NE) atomicAdd(&cnt[dst[i]], 1);
}

__global__ void k_scan(int* __restrict__ cc, int* __restrict__ rowptr) {
    __shared__ int part[1024];
    int t = threadIdx.x;
    const int CHK = 49;  // 1024*49 = 50176 >= 50000
    int base = t * CHK;
    int s = 0;
    for (int i = 0; i < CHK; i++) {
        int idx = base + i;
        if (idx < NN) s += cc[idx];
    }
    part[t] = s;
    __syncthreads();
    for (int off = 1; off < 1024; off <<= 1) {
        int v = (t >= off) ? part[t - off] : 0;
        __syncthreads();
        part[t] += v;
        __syncthreads();
    }
    int running = part[t] - s;  // exclusive prefix
    for (int i = 0; i < CHK; i++) {
        int idx = base + i;
        if (idx < NN) {
            int c = cc[idx];
            rowptr[idx] = running;
            cc[idx] = running;   // becomes scatter cursor
            running += c;
        }
    }
    if (t == 1023) rowptr[NN] = running;
}

__global__ void k_scatter(const int* __restrict__ src, const int* __restrict__ dst,
                          int* __restrict__ cursor, int* __restrict__ ssrc) {
    int i = blockIdx.x * 256 + threadIdx.x;
    if (i < NE) {
        int d = dst[i];
        int pos = atomicAdd(&cursor[d], 1);
        ssrc[pos] = src[i];
    }
}

// ---------------- W -> bf16 transposed (Wt[j][k] = W[k][j]) ----------------
__global__ void k_prepw(const float* __restrict__ W1, const float* __restrict__ W2,
                        const float* __restrict__ W3, unsigned short* __restrict__ Wt) {
    int b = blockIdx.x;          // 768 = 3 layers * 256 k-rows
    int L = b >> 8, k = b & 255;
    const float* W = (L == 0) ? W1 : ((L == 1) ? W2 : W3);
    int j = threadIdx.x;
    Wt[L * 65536 + j * 256 + k] = f2bf(W[k * 256 + j]);
}

// ---------------- GEMM: feat = BN(A) @ W  (bf16 MFMA, fp32 acc) ----------------
// block: 256 thr = 4 waves; tile 64 rows x 256 cols; wave w owns cols [64w,64w+64)
// = head w. Fused epilogue: el/er attention dots + bf16 feat store.
__launch_bounds__(256, 2)
__global__ void k_gemm(const float* __restrict__ A, const unsigned short* __restrict__ Wt,
                       const float* __restrict__ bnscale, const float* __restrict__ bnshift,
                       int use_bn, const float* __restrict__ al, const float* __restrict__ ar,
                       unsigned short* __restrict__ feat16, float* __restrict__ el,
                       float* __restrict__ er) {
    constexpr int AP = 264;  // A lds pitch in bf16 elems
    constexpr int BP = 40;   // B lds pitch
    __shared__ __align__(16) unsigned short Alds[64 * AP];
    __shared__ __align__(16) unsigned short Blds[256 * BP];
    const int tid = threadIdx.x;
    const int rowbase = blockIdx.x * 64;

    // stage A: 64 rows x K=256, fp32 -> (BN) -> bf16
    {
        int r = tid >> 6;
        int c4 = tid & 63;
        for (int it = 0; it < 16; it++) {
            int rr = it * 4 + r;
            int gr = rowbase + rr;
            float4 v = make_float4(0.f, 0.f, 0.f, 0.f);
            if (gr < NN) v = *(const float4*)(A + (size_t)gr * 256 + c4 * 4);
            if (use_bn) {
                float4 sc = *(const float4*)(bnscale + c4 * 4);
                float4 sh = *(const float4*)(bnshift + c4 * 4);
                v.x = v.x * sc.x + sh.x;
                v.y = v.y * sc.y + sh.y;
                v.z = v.z * sc.z + sh.z;
                v.w = v.w * sc.w + sh.w;
            }
            ushort4 pv;
            pv.x = f2bf(v.x); pv.y = f2bf(v.y); pv.z = f2bf(v.z); pv.w = f2bf(v.w);
            *(ushort4*)(&Alds[rr * AP + c4 * 4]) = pv;
        }
    }

    f32x4 acc[4][4];
    for (int i = 0; i < 4; i++)
        for (int j = 0; j < 4; j++)
            acc[i][j] = (f32x4){0.f, 0.f, 0.f, 0.f};

    const int lane = tid & 63, w = tid >> 6;
    const int mm = lane & 15, q = lane >> 4;

    for (int kc = 0; kc < 8; kc++) {
        __syncthreads();
        for (int i = 0; i < 4; i++) {
            int idx = i * 256 + tid;
            int j = idx >> 2, part = idx & 3;
            uint4 vv = *(const uint4*)(Wt + j * 256 + kc * 32 + part * 8);
            *(uint4*)(&Blds[j * BP + part * 8]) = vv;
        }
        __syncthreads();
        bf16x8 a[4], b[4];
        for (int i = 0; i < 4; i++)
            a[i] = *(const bf16x8*)(&Alds[(16 * i + mm) * AP + kc * 32 + q * 8]);
        for (int j = 0; j < 4; j++)
            b[j] = *(const bf16x8*)(&Blds[(64 * w + 16 * j + mm) * BP + q * 8]);
        for (int i = 0; i < 4; i++)
            for (int j = 0; j < 4; j++)
                acc[i][j] = __builtin_amdgcn_mfma_f32_16x16x32_bf16(a[i], b[j], acc[i][j], 0, 0, 0);
    }

    // ---- fused el/er: head w cols are exactly this wave's 64 cols ----
    float alv[4], arv[4];
    for (int j = 0; j < 4; j++) {
        alv[j] = al[w * 64 + 16 * j + mm];
        arv[j] = ar[w * 64 + 16 * j + mm];
    }
    for (int i = 0; i < 4; i++) {
        for (int r = 0; r < 4; r++) {
            int gr = rowbase + 16 * i + q * 4 + r;
            float se = 0.f, sr = 0.f;
            for (int j = 0; j < 4; j++) {
                se += acc[i][j][r] * alv[j];
                sr += acc[i][j][r] * arv[j];
            }
            for (int off = 1; off < 16; off <<= 1) {
                se += __shfl_xor(se, off, 64);
                sr += __shfl_xor(sr, off, 64);
            }
            if (mm == 0 && gr < NN) {
                el[gr * 4 + w] = se;
                er[gr * 4 + w] = sr;
            }
        }
    }

    // ---- feat store as bf16 (C/D layout: col=lane&15, row=(lane>>4)*4+reg) ----
    for (int i = 0; i < 4; i++) {
        for (int j = 0; j < 4; j++) {
            int gc = 64 * w + 16 * j + mm;
            for (int r = 0; r < 4; r++) {
                int gr = rowbase + 16 * i + q * 4 + r;
                if (gr < NN) feat16[(size_t)gr * 256 + gc] = f2bf(acc[i][j][r]);
            }
        }
    }
}

// ---------------- per-dst softmax + weighted aggregation (bf16 gather) ----------------
// one wave per destination node; lane l owns channels [4l, 4l+4); head h = l>>4
// max via monotonicity: max_e leaky(el[s]+erh) = leaky(max_e el[s] + erh)
__launch_bounds__(256)
__global__ void k_agg(const unsigned short* __restrict__ feat16, const float* __restrict__ el,
                      const float* __restrict__ er, const int* __restrict__ rowptr,
                      const int* __restrict__ ssrc, const float* __restrict__ resid,
                      const float* __restrict__ bnscale, const float* __restrict__ bnshift,
                      int use_bn, const float* __restrict__ bias, int act,
                      float* __restrict__ out, int final_mean) {
    int n = blockIdx.x * 4 + (threadIdx.x >> 6);
    int l = threadIdx.x & 63;
    int h = l >> 4;
    int beg = rowptr[n], end = rowptr[n + 1];
    float erh = er[n * 4 + h];

    // pass 1: max of el over in-edges (no exp needed)
    float mx = -1e30f;
    for (int e = beg; e < end; e++) {
        int s = ssrc[e];
        mx = fmaxf(mx, el[s * 4 + h]);
    }
    float m = mx + erh;
    m = (m > 0.f) ? m : SLOPE_A * m;

    // pass 2: fused denom + weighted gather-accumulate
    float d = 0.f;
    float4 acc = make_float4(0.f, 0.f, 0.f, 0.f);
    for (int e = beg; e < end; e++) {
        int s = ssrc[e];
        float sc = el[s * 4 + h] + erh;
        sc = (sc > 0.f) ? sc : SLOPE_A * sc;
        float wgt = __expf(sc - m);
        d += wgt;
        ushort4 fv = *(const ushort4*)(feat16 + (size_t)s * 256 + l * 4);
        acc.x += bf2f(fv.x) * wgt;
        acc.y += bf2f(fv.y) * wgt;
        acc.z += bf2f(fv.z) * wgt;
        acc.w += bf2f(fv.w) * wgt;
    }
    float invd = 1.f / fmaxf(d, 1e-9f);
    acc.x *= invd; acc.y *= invd; acc.z *= invd; acc.w *= invd;

    // residual (+BN) + bias
    float4 r = *(const float4*)(resid + (size_t)n * 256 + l * 4);
    if (use_bn) {
        float4 sc4 = *(const float4*)(bnscale + l * 4);
        float4 sh4 = *(const float4*)(bnshift + l * 4);
        r.x = r.x * sc4.x + sh4.x;
        r.y = r.y * sc4.y + sh4.y;
        r.z = r.z * sc4.z + sh4.z;
        r.w = r.w * sc4.w + sh4.w;
    }
    float4 bb = *(const float4*)(bias + l * 4);
    acc.x += r.x + bb.x; acc.y += r.y + bb.y;
    acc.z += r.z + bb.z; acc.w += r.w + bb.w;
    if (act) {
        acc.x = (acc.x > 0.f) ? acc.x : SLOPE_R * acc.x;
        acc.y = (acc.y > 0.f) ? acc.y : SLOPE_R * acc.y;
        acc.z = (acc.z > 0.f) ? acc.z : SLOPE_R * acc.z;
        acc.w = (acc.w > 0.f) ? acc.w : SLOPE_R * acc.w;
    }

    if (!final_mean) {
        *(float4*)(out + (size_t)n * 256 + l * 4) = acc;
    } else {
        acc.x += __shfl_xor(acc.x, 16, 64); acc.x += __shfl_xor(acc.x, 32, 64);
        acc.y += __shfl_xor(acc.y, 16, 64); acc.y += __shfl_xor(acc.y, 32, 64);
        acc.z += __shfl_xor(acc.z, 16, 64); acc.z += __shfl_xor(acc.z, 32, 64);
        acc.w += __shfl_xor(acc.w, 16, 64); acc.w += __shfl_xor(acc.w, 32, 64);
        if (l < 16) {
            acc.x *= 0.25f; acc.y *= 0.25f; acc.z *= 0.25f; acc.w *= 0.25f;
            *(float4*)(out + (size_t)n * 64 + l * 4) = acc;
        }
    }
}

// ---------------- BatchNorm stats ----------------
__global__ void k_bnstats(const float* __restrict__ hh, float* __restrict__ sums) {
    int t = threadIdx.x;
    int b = blockIdx.x;
    int r0 = b * 196, r1 = min(r0 + 196, NN);
    float s = 0.f, s2 = 0.f;
    for (int r = r0; r < r1; r++) {
        float v = hh[(size_t)r * 256 + t];
        s += v; s2 += v * v;
    }
    atomicAdd(&sums[t], s);
    atomicAdd(&sums[256 + t], s2);
}

__global__ void k_bnfinal(const float* __restrict__ sums, const float* __restrict__ g,
                          const float* __restrict__ be, float* __restrict__ scale,
                          float* __restrict__ shift) {
    int t = threadIdx.x;
    float mu = sums[t] * (1.f / NN);
    float var = sums[256 + t] * (1.f / NN) - mu * mu;
    float rs = rsqrtf(var + 1e-5f);
    float sc = rs * g[t];
    scale[t] = sc;
    shift[t] = be[t] - mu * sc;
}

// ---------------- launcher ----------------
extern "C" void kernel_launch(void* const* d_in, const int* in_sizes, int n_in,
                              void* d_out, int out_size, void* d_ws, size_t ws_size,
                              hipStream_t stream) {
    const float* x   = (const float*)d_in[0];
    const int* src   = (const int*)d_in[1];
    const int* dst   = (const int*)d_in[2];
    const float* W1  = (const float*)d_in[3];
    const float* al1 = (const float*)d_in[4];
    const float* ar1 = (const float*)d_in[5];
    const float* b1  = (const float*)d_in[6];
    const float* W2  = (const float*)d_in[7];
    const float* al2 = (const float*)d_in[8];
    const float* ar2 = (const float*)d_in[9];
    const float* b2  = (const float*)d_in[10];
    const float* W3  = (const float*)d_in[11];
    const float* al3 = (const float*)d_in[12];
    const float* ar3 = (const float*)d_in[13];
    const float* b3  = (const float*)d_in[14];
    const float* g1  = (const float*)d_in[15];
    const float* be1 = (const float*)d_in[16];
    const float* g2  = (const float*)d_in[17];
    const float* be2 = (const float*)d_in[18];
    float* out = (float*)d_out;

    char* ws = (char*)d_ws;
    size_t off = 0;
    auto alloc = [&](size_t bytes) {
        void* p = ws + off;
        off += (bytes + 255) & ~(size_t)255;
        return p;
    };
    int* rowptr = (int*)alloc((NN + 1) * sizeof(int));
    int* cursor = (int*)alloc(NN * sizeof(int));
    int* ssrc   = (int*)alloc(NE * sizeof(int));
    unsigned short* feat16 = (unsigned short*)alloc((size_t)NN * 256 * sizeof(unsigned short));
    float* hbuf = (float*)alloc((size_t)NN * 256 * sizeof(float));
    float* el   = (float*)alloc((size_t)NN * 4 * sizeof(float));
    float* er   = (float*)alloc((size_t)NN * 4 * sizeof(float));
    unsigned short* Wt = (unsigned short*)alloc(3 * 65536 * sizeof(unsigned short));
    float* bnsums  = (float*)alloc(512 * sizeof(float));
    float* bnscale = (float*)alloc(256 * sizeof(float));
    float* bnshift = (float*)alloc(256 * sizeof(float));

    // CSR build (graph identical for all layers)
    hipMemsetAsync(cursor, 0, NN * sizeof(int), stream);
    k_hist<<<(NE + 255) / 256, 256, 0, stream>>>(dst, cursor);
    k_scan<<<1, 1024, 0, stream>>>(cursor, rowptr);
    k_scatter<<<(NE + 255) / 256, 256, 0, stream>>>(src, dst, cursor, ssrc);
    k_prepw<<<768, 256, 0, stream>>>(W1, W2, W3, Wt);

    const int GB = (NN + 63) / 64;  // 782
    const int NB = NN / 4;          // 12500

    // ---- layer 1 ----
    k_gemm<<<GB, 256, 0, stream>>>(x, Wt, nullptr, nullptr, 0, al1, ar1, feat16, el, er);
    k_agg<<<NB, 256, 0, stream>>>(feat16, el, er, rowptr, ssrc, x,
                                  nullptr, nullptr, 0, b1, 1, hbuf, 0);
    hipMemsetAsync(bnsums, 0, 512 * sizeof(float), stream);
    k_bnstats<<<256, 256, 0, stream>>>(hbuf, bnsums);
    k_bnfinal<<<1, 256, 0, stream>>>(bnsums, g1, be1, bnscale, bnshift);

    // ---- layer 2 ----
    k_gemm<<<GB, 256, 0, stream>>>(hbuf, Wt + 65536, bnscale, bnshift, 1, al2, ar2, feat16, el, er);
    k_agg<<<NB, 256, 0, stream>>>(feat16, el, er, rowptr, ssrc, hbuf,
                                  bnscale, bnshift, 1, b2, 1, hbuf, 0);
    hipMemsetAsync(bnsums, 0, 512 * sizeof(float), stream);
    k_bnstats<<<256, 256, 0, stream>>>(hbuf, bnsums);
    k_bnfinal<<<1, 256, 0, stream>>>(bnsums, g2, be2, bnscale, bnshift);

    // ---- layer 3 ----
    k_gemm<<<GB, 256, 0, stream>>>(hbuf, Wt + 131072, bnscale, bnshift, 1, al3, ar3, feat16, el, er);
    k_agg<<<NB, 256, 0, stream>>>(feat16, el, er, rowptr, ssrc, hbuf,
                                  bnscale, bnshift, 1, b3, 0, out, 1);
}

// Round 3
// 728.805 us; speedup vs baseline: 1.4992x; 1.3139x over previous
//
#include <hip/hip_runtime.h>

constexpr int NN = 50000;     // nodes
constexpr int NE = 800000;    // edges
constexpr float SLOPE_A = 0.2f;   // attention leaky_relu
constexpr float SLOPE_R = 0.01f;  // activation leaky_relu

typedef __attribute__((ext_vector_type(8))) short bf16x8;
typedef __attribute__((ext_vector_type(4))) float f32x4;

__device__ __forceinline__ unsigned short f2bf(float f) {
    union { float f; unsigned u; } v; v.f = f;
    unsigned u = v.u;
    unsigned r = u + 0x7fffu + ((u >> 16) & 1u);  // round-to-nearest-even
    return (unsigned short)(r >> 16);
}
__device__ __forceinline__ float bf2f(unsigned short s) {
    union { unsigned u; float f; } v; v.u = ((unsigned)s) << 16;
    return v.f;
}

// ---------------- CSR build ----------------
__global__ void k_hist(const int* __restrict__ dst, int* __restrict__ cnt) {
    int i = blockIdx.x * 256 + threadIdx.x;
    if (i < NE) atomicAdd(&cnt[dst[i]], 1);
}

__global__ void k_scan(int* __restrict__ cc, int* __restrict__ rowptr) {
    __shared__ int part[1024];
    int t = threadIdx.x;
    const int CHK = 49;  // 1024*49 = 50176 >= 50000
    int base = t * CHK;
    int s = 0;
    for (int i = 0; i < CHK; i++) {
        int idx = base + i;
        if (idx < NN) s += cc[idx];
    }
    part[t] = s;
    __syncthreads();
    for (int off = 1; off < 1024; off <<= 1) {
        int v = (t >= off) ? part[t - off] : 0;
        __syncthreads();
        part[t] += v;
        __syncthreads();
    }
    int running = part[t] - s;  // exclusive prefix
    for (int i = 0; i < CHK; i++) {
        int idx = base + i;
        if (idx < NN) {
            int c = cc[idx];
            rowptr[idx] = running;
            cc[idx] = running;   // becomes scatter cursor
            running += c;
        }
    }
    if (t == 1023) rowptr[NN] = running;
}

__global__ void k_scatter(const int* __restrict__ src, const int* __restrict__ dst,
                          int* __restrict__ cursor, int* __restrict__ ssrc) {
    int i = blockIdx.x * 256 + threadIdx.x;
    if (i < NE) {
        int d = dst[i];
        int pos = atomicAdd(&cursor[d], 1);
        ssrc[pos] = src[i];
    }
}

// ---------------- W -> bf16 transposed (Wt[j][k] = W[k][j]) ----------------
__global__ void k_prepw(const float* __restrict__ W1, const float* __restrict__ W2,
                        const float* __restrict__ W3, unsigned short* __restrict__ Wt) {
    int b = blockIdx.x;          // 768 = 3 layers * 256 k-rows
    int L = b >> 8, k = b & 255;
    const float* W = (L == 0) ? W1 : ((L == 1) ? W2 : W3);
    int j = threadIdx.x;
    Wt[L * 65536 + j * 256 + k] = f2bf(W[k * 256 + j]);
}

// ---------------- GEMM: feat = BN(A) @ W  (bf16 MFMA, fp32 acc) ----------------
// block: 256 thr = 4 waves; tile 64 rows x 256 cols; wave w owns cols [64w,64w+64)
// = head w. B fragments read directly from global (L2-resident 128KB) in MFMA
// layout -- no B LDS staging, only 1 barrier. Fused epilogue: el/er + bf16 store.
__launch_bounds__(256, 2)
__global__ void k_gemm(const float* __restrict__ A, const unsigned short* __restrict__ Wt,
                       const float* __restrict__ bnscale, const float* __restrict__ bnshift,
                       int use_bn, const float* __restrict__ al, const float* __restrict__ ar,
                       unsigned short* __restrict__ feat16, float* __restrict__ el,
                       float* __restrict__ er) {
    constexpr int AP = 264;  // A lds pitch in bf16 elems (row start 16B-aligned)
    __shared__ __align__(16) unsigned short Alds[64 * AP];
    const int tid = threadIdx.x;
    const int rowbase = blockIdx.x * 64;

    // stage A: 64 rows x K=256, fp32 -> (BN) -> bf16
    {
        int r = tid >> 6;
        int c4 = tid & 63;
        for (int it = 0; it < 16; it++) {
            int rr = it * 4 + r;
            int gr = rowbase + rr;
            float4 v = make_float4(0.f, 0.f, 0.f, 0.f);
            if (gr < NN) v = *(const float4*)(A + (size_t)gr * 256 + c4 * 4);
            if (use_bn) {
                float4 sc = *(const float4*)(bnscale + c4 * 4);
                float4 sh = *(const float4*)(bnshift + c4 * 4);
                v.x = v.x * sc.x + sh.x;
                v.y = v.y * sc.y + sh.y;
                v.z = v.z * sc.z + sh.z;
                v.w = v.w * sc.w + sh.w;
            }
            ushort4 pv;
            pv.x = f2bf(v.x); pv.y = f2bf(v.y); pv.z = f2bf(v.z); pv.w = f2bf(v.w);
            *(ushort4*)(&Alds[rr * AP + c4 * 4]) = pv;
        }
    }
    __syncthreads();

    f32x4 acc[4][4];
    for (int i = 0; i < 4; i++)
        for (int j = 0; j < 4; j++)
            acc[i][j] = (f32x4){0.f, 0.f, 0.f, 0.f};

    const int lane = tid & 63, w = tid >> 6;
    const int mm = lane & 15, q = lane >> 4;

    // B fragment base: lane (mm,q) of wave w, col-block j, chunk kc needs
    // Wt[(64w+16j+mm)*256 + kc*32 + q*8 .. +8]
    const unsigned short* bbase = Wt + ((size_t)(64 * w + mm)) * 256 + q * 8;

#pragma unroll
    for (int kc = 0; kc < 8; kc++) {
        bf16x8 a[4], b[4];
        for (int i = 0; i < 4; i++)
            a[i] = *(const bf16x8*)(&Alds[(16 * i + mm) * AP + kc * 32 + q * 8]);
        for (int j = 0; j < 4; j++)
            b[j] = *(const bf16x8*)(bbase + j * (16 * 256) + kc * 32);
        for (int i = 0; i < 4; i++)
            for (int j = 0; j < 4; j++)
                acc[i][j] = __builtin_amdgcn_mfma_f32_16x16x32_bf16(a[i], b[j], acc[i][j], 0, 0, 0);
    }

    // ---- fused el/er: head w cols are exactly this wave's 64 cols ----
    float alv[4], arv[4];
    for (int j = 0; j < 4; j++) {
        alv[j] = al[w * 64 + 16 * j + mm];
        arv[j] = ar[w * 64 + 16 * j + mm];
    }
    for (int i = 0; i < 4; i++) {
        for (int r = 0; r < 4; r++) {
            int gr = rowbase + 16 * i + q * 4 + r;
            float se = 0.f, sr = 0.f;
            for (int j = 0; j < 4; j++) {
                se += acc[i][j][r] * alv[j];
                sr += acc[i][j][r] * arv[j];
            }
            for (int off = 1; off < 16; off <<= 1) {
                se += __shfl_xor(se, off, 64);
                sr += __shfl_xor(sr, off, 64);
            }
            if (mm == 0 && gr < NN) {
                el[gr * 4 + w] = se;
                er[gr * 4 + w] = sr;
            }
        }
    }

    // ---- feat store as bf16 (C/D layout: col=lane&15, row=(lane>>4)*4+reg) ----
    for (int i = 0; i < 4; i++) {
        for (int j = 0; j < 4; j++) {
            int gc = 64 * w + 16 * j + mm;
            for (int r = 0; r < 4; r++) {
                int gr = rowbase + 16 * i + q * 4 + r;
                if (gr < NN) feat16[(size_t)gr * 256 + gc] = f2bf(acc[i][j][r]);
            }
        }
    }
}

// ---------------- per-dst softmax + weighted aggregation (bf16 gather) ----------------
// one wave per destination node; lane l owns channels [4l, 4l+4); head h = l>>4.
// No-max softmax: scores are bounded (BN-normalized inputs, |sc| << 80), so
// exp(sc)/sum(exp(sc)) is computed directly -- single gather pass, unrolled x4
// with scalarized (SMEM) edge indices for 4 in-flight gathers.
__launch_bounds__(256)
__global__ void k_agg(const unsigned short* __restrict__ feat16, const float* __restrict__ el,
                      const float* __restrict__ er, const int* __restrict__ rowptr,
                      const int* __restrict__ ssrc, const float* __restrict__ resid,
                      const float* __restrict__ bnscale, const float* __restrict__ bnshift,
                      int use_bn, const float* __restrict__ bias, int act,
                      float* __restrict__ out, int final_mean) {
    int n = __builtin_amdgcn_readfirstlane(blockIdx.x * 4 + (threadIdx.x >> 6));
    int l = threadIdx.x & 63;
    int h = l >> 4;
    int beg = rowptr[n], end = rowptr[n + 1];
    float erh = er[n * 4 + h];

    float d = 0.f;
    float4 acc = make_float4(0.f, 0.f, 0.f, 0.f);

    int e = beg;
    for (; e + 4 <= end; e += 4) {
        int s0 = ssrc[e + 0], s1 = ssrc[e + 1], s2 = ssrc[e + 2], s3 = ssrc[e + 3];
        float c0 = el[s0 * 4 + h] + erh;
        float c1 = el[s1 * 4 + h] + erh;
        float c2 = el[s2 * 4 + h] + erh;
        float c3 = el[s3 * 4 + h] + erh;
        ushort4 f0 = *(const ushort4*)(feat16 + (size_t)s0 * 256 + l * 4);
        ushort4 f1 = *(const ushort4*)(feat16 + (size_t)s1 * 256 + l * 4);
        ushort4 f2 = *(const ushort4*)(feat16 + (size_t)s2 * 256 + l * 4);
        ushort4 f3 = *(const ushort4*)(feat16 + (size_t)s3 * 256 + l * 4);
        c0 = (c0 > 0.f) ? c0 : SLOPE_A * c0;
        c1 = (c1 > 0.f) ? c1 : SLOPE_A * c1;
        c2 = (c2 > 0.f) ? c2 : SLOPE_A * c2;
        c3 = (c3 > 0.f) ? c3 : SLOPE_A * c3;
        float w0 = __expf(c0), w1 = __expf(c1), w2 = __expf(c2), w3 = __expf(c3);
        d += (w0 + w1) + (w2 + w3);
        acc.x += bf2f(f0.x) * w0; acc.y += bf2f(f0.y) * w0;
        acc.z += bf2f(f0.z) * w0; acc.w += bf2f(f0.w) * w0;
        acc.x += bf2f(f1.x) * w1; acc.y += bf2f(f1.y) * w1;
        acc.z += bf2f(f1.z) * w1; acc.w += bf2f(f1.w) * w1;
        acc.x += bf2f(f2.x) * w2; acc.y += bf2f(f2.y) * w2;
        acc.z += bf2f(f2.z) * w2; acc.w += bf2f(f2.w) * w2;
        acc.x += bf2f(f3.x) * w3; acc.y += bf2f(f3.y) * w3;
        acc.z += bf2f(f3.z) * w3; acc.w += bf2f(f3.w) * w3;
    }
    for (; e < end; e++) {
        int s = ssrc[e];
        float sc = el[s * 4 + h] + erh;
        sc = (sc > 0.f) ? sc : SLOPE_A * sc;
        float wgt = __expf(sc);
        ushort4 fv = *(const ushort4*)(feat16 + (size_t)s * 256 + l * 4);
        d += wgt;
        acc.x += bf2f(fv.x) * wgt;
        acc.y += bf2f(fv.y) * wgt;
        acc.z += bf2f(fv.z) * wgt;
        acc.w += bf2f(fv.w) * wgt;
    }

    float invd = 1.f / fmaxf(d, 1e-9f);
    acc.x *= invd; acc.y *= invd; acc.z *= invd; acc.w *= invd;

    // residual (+BN) + bias
    float4 r = *(const float4*)(resid + (size_t)n * 256 + l * 4);
    if (use_bn) {
        float4 sc4 = *(const float4*)(bnscale + l * 4);
        float4 sh4 = *(const float4*)(bnshift + l * 4);
        r.x = r.x * sc4.x + sh4.x;
        r.y = r.y * sc4.y + sh4.y;
        r.z = r.z * sc4.z + sh4.z;
        r.w = r.w * sc4.w + sh4.w;
    }
    float4 bb = *(const float4*)(bias + l * 4);
    acc.x += r.x + bb.x; acc.y += r.y + bb.y;
    acc.z += r.z + bb.z; acc.w += r.w + bb.w;
    if (act) {
        acc.x = (acc.x > 0.f) ? acc.x : SLOPE_R * acc.x;
        acc.y = (acc.y > 0.f) ? acc.y : SLOPE_R * acc.y;
        acc.z = (acc.z > 0.f) ? acc.z : SLOPE_R * acc.z;
        acc.w = (acc.w > 0.f) ? acc.w : SLOPE_R * acc.w;
    }

    if (!final_mean) {
        *(float4*)(out + (size_t)n * 256 + l * 4) = acc;
    } else {
        acc.x += __shfl_xor(acc.x, 16, 64); acc.x += __shfl_xor(acc.x, 32, 64);
        acc.y += __shfl_xor(acc.y, 16, 64); acc.y += __shfl_xor(acc.y, 32, 64);
        acc.z += __shfl_xor(acc.z, 16, 64); acc.z += __shfl_xor(acc.z, 32, 64);
        acc.w += __shfl_xor(acc.w, 16, 64); acc.w += __shfl_xor(acc.w, 32, 64);
        if (l < 16) {
            acc.x *= 0.25f; acc.y *= 0.25f; acc.z *= 0.25f; acc.w *= 0.25f;
            *(float4*)(out + (size_t)n * 64 + l * 4) = acc;
        }
    }
}

// ---------------- BatchNorm stats ----------------
__global__ void k_bnstats(const float* __restrict__ hh, float* __restrict__ sums) {
    int t = threadIdx.x;
    int b = blockIdx.x;
    int r0 = b * 196, r1 = min(r0 + 196, NN);
    float s = 0.f, s2 = 0.f;
    for (int r = r0; r < r1; r++) {
        float v = hh[(size_t)r * 256 + t];
        s += v; s2 += v * v;
    }
    atomicAdd(&sums[t], s);
    atomicAdd(&sums[256 + t], s2);
}

__global__ void k_bnfinal(const float* __restrict__ sums, const float* __restrict__ g,
                          const float* __restrict__ be, float* __restrict__ scale,
                          float* __restrict__ shift) {
    int t = threadIdx.x;
    float mu = sums[t] * (1.f / NN);
    float var = sums[256 + t] * (1.f / NN) - mu * mu;
    float rs = rsqrtf(var + 1e-5f);
    float sc = rs * g[t];
    scale[t] = sc;
    shift[t] = be[t] - mu * sc;
}

// ---------------- launcher ----------------
extern "C" void kernel_launch(void* const* d_in, const int* in_sizes, int n_in,
                              void* d_out, int out_size, void* d_ws, size_t ws_size,
                              hipStream_t stream) {
    const float* x   = (const float*)d_in[0];
    const int* src   = (const int*)d_in[1];
    const int* dst   = (const int*)d_in[2];
    const float* W1  = (const float*)d_in[3];
    const float* al1 = (const float*)d_in[4];
    const float* ar1 = (const float*)d_in[5];
    const float* b1  = (const float*)d_in[6];
    const float* W2  = (const float*)d_in[7];
    const float* al2 = (const float*)d_in[8];
    const float* ar2 = (const float*)d_in[9];
    const float* b2  = (const float*)d_in[10];
    const float* W3  = (const float*)d_in[11];
    const float* al3 = (const float*)d_in[12];
    const float* ar3 = (const float*)d_in[13];
    const float* b3  = (const float*)d_in[14];
    const float* g1  = (const float*)d_in[15];
    const float* be1 = (const float*)d_in[16];
    const float* g2  = (const float*)d_in[17];
    const float* be2 = (const float*)d_in[18];
    float* out = (float*)d_out;

    char* ws = (char*)d_ws;
    size_t off = 0;
    auto alloc = [&](size_t bytes) {
        void* p = ws + off;
        off += (bytes + 255) & ~(size_t)255;
        return p;
    };
    int* rowptr = (int*)alloc((NN + 1) * sizeof(int));
    int* cursor = (int*)alloc(NN * sizeof(int));
    int* ssrc   = (int*)alloc(NE * sizeof(int));
    unsigned short* feat16 = (unsigned short*)alloc((size_t)NN * 256 * sizeof(unsigned short));
    float* hbuf = (float*)alloc((size_t)NN * 256 * sizeof(float));
    float* el   = (float*)alloc((size_t)NN * 4 * sizeof(float));
    float* er   = (float*)alloc((size_t)NN * 4 * sizeof(float));
    unsigned short* Wt = (unsigned short*)alloc(3 * 65536 * sizeof(unsigned short));
    float* bnsums  = (float*)alloc(512 * sizeof(float));
    float* bnscale = (float*)alloc(256 * sizeof(float));
    float* bnshift = (float*)alloc(256 * sizeof(float));

    // CSR build (graph identical for all layers)
    hipMemsetAsync(cursor, 0, NN * sizeof(int), stream);
    k_hist<<<(NE + 255) / 256, 256, 0, stream>>>(dst, cursor);
    k_scan<<<1, 1024, 0, stream>>>(cursor, rowptr);
    k_scatter<<<(NE + 255) / 256, 256, 0, stream>>>(src, dst, cursor, ssrc);
    k_prepw<<<768, 256, 0, stream>>>(W1, W2, W3, Wt);

    const int GB = (NN + 63) / 64;  // 782
    const int NB = NN / 4;          // 12500

    // ---- layer 1 ----
    k_gemm<<<GB, 256, 0, stream>>>(x, Wt, nullptr, nullptr, 0, al1, ar1, feat16, el, er);
    k_agg<<<NB, 256, 0, stream>>>(feat16, el, er, rowptr, ssrc, x,
                                  nullptr, nullptr, 0, b1, 1, hbuf, 0);
    hipMemsetAsync(bnsums, 0, 512 * sizeof(float), stream);
    k_bnstats<<<256, 256, 0, stream>>>(hbuf, bnsums);
    k_bnfinal<<<1, 256, 0, stream>>>(bnsums, g1, be1, bnscale, bnshift);

    // ---- layer 2 ----
    k_gemm<<<GB, 256, 0, stream>>>(hbuf, Wt + 65536, bnscale, bnshift, 1, al2, ar2, feat16, el, er);
    k_agg<<<NB, 256, 0, stream>>>(feat16, el, er, rowptr, ssrc, hbuf,
                                  bnscale, bnshift, 1, b2, 1, hbuf, 0);
    hipMemsetAsync(bnsums, 0, 512 * sizeof(float), stream);
    k_bnstats<<<256, 256, 0, stream>>>(hbuf, bnsums);
    k_bnfinal<<<1, 256, 0, stream>>>(bnsums, g2, be2, bnscale, bnshift);

    // ---- layer 3 ----
    k_gemm<<<GB, 256, 0, stream>>>(hbuf, Wt + 131072, bnscale, bnshift, 1, al3, ar3, feat16, el, er);
    k_agg<<<NB, 256, 0, stream>>>(feat16, el, er, rowptr, ssrc, hbuf,
                                  bnscale, bnshift, 1, b3, 0, out, 1);
}

// Round 4
// 615.787 us; speedup vs baseline: 1.7744x; 1.1835x over previous
//
#include <hip/hip_runtime.h>

constexpr int NN = 50000;     // nodes
constexpr int NE = 800000;    // edges
constexpr float SLOPE_A = 0.2f;   // attention leaky_relu
constexpr float SLOPE_R = 0.01f;  // activation leaky_relu
constexpr int SCB = 196;      // scan blocks: 196*256 = 50176 >= NN

typedef __attribute__((ext_vector_type(8))) short bf16x8;
typedef __attribute__((ext_vector_type(4))) float f32x4;

__device__ __forceinline__ unsigned short f2bf(float f) {
    union { float f; unsigned u; } v; v.f = f;
    unsigned u = v.u;
    unsigned r = u + 0x7fffu + ((u >> 16) & 1u);  // round-to-nearest-even
    return (unsigned short)(r >> 16);
}
__device__ __forceinline__ float bf2f(unsigned short s) {
    union { unsigned u; float f; } v; v.u = ((unsigned)s) << 16;
    return v.f;
}

// ---------------- CSR build ----------------
__global__ void k_hist(const int* __restrict__ dst, int* __restrict__ cnt) {
    int i = blockIdx.x * 256 + threadIdx.x;
    if (i < NE) atomicAdd(&cnt[dst[i]], 1);
}

// phase 1: per-block (256-elem) local exclusive scan + block sum
__global__ void k_scan1(const int* __restrict__ cnt, int* __restrict__ loc,
                        int* __restrict__ bsum) {
    __shared__ int sh[256];
    int t = threadIdx.x;
    int i = blockIdx.x * 256 + t;
    int v = (i < NN) ? cnt[i] : 0;
    sh[t] = v;
    __syncthreads();
    for (int off = 1; off < 256; off <<= 1) {
        int tmp = (t >= off) ? sh[t - off] : 0;
        __syncthreads();
        sh[t] += tmp;
        __syncthreads();
    }
    loc[i] = sh[t] - v;              // exclusive local prefix
    if (t == 255) bsum[blockIdx.x] = sh[255];
}

// phase 2: scan the 196 block sums (single small block); writes rowptr[NN]=total
__global__ void k_scan2(const int* __restrict__ bsum, int* __restrict__ boff,
                        int* __restrict__ rowptr) {
    __shared__ int sh[256];
    int t = threadIdx.x;
    int v = (t < SCB) ? bsum[t] : 0;
    sh[t] = v;
    __syncthreads();
    for (int off = 1; off < 256; off <<= 1) {
        int tmp = (t >= off) ? sh[t - off] : 0;
        __syncthreads();
        sh[t] += tmp;
        __syncthreads();
    }
    if (t < SCB) boff[t] = sh[t] - v;  // exclusive
    if (t == 255) rowptr[NN] = sh[255];
}

// phase 3: global offsets -> rowptr + cursor
__global__ void k_scan3(const int* __restrict__ loc, const int* __restrict__ boff,
                        int* __restrict__ rowptr, int* __restrict__ cursor) {
    int i = blockIdx.x * 256 + threadIdx.x;
    if (i < NN) {
        int r = loc[i] + boff[blockIdx.x];
        rowptr[i] = r;
        cursor[i] = r;
    }
}

__global__ void k_scatter(const int* __restrict__ src, const int* __restrict__ dst,
                          int* __restrict__ cursor, int* __restrict__ ssrc) {
    int i = blockIdx.x * 256 + threadIdx.x;
    if (i < NE) {
        int d = dst[i];
        int pos = atomicAdd(&cursor[d], 1);
        ssrc[pos] = src[i];
    }
}

// ---------------- W -> bf16 transposed (Wt[j][k] = W[k][j]) ----------------
__global__ void k_prepw(const float* __restrict__ W1, const float* __restrict__ W2,
                        const float* __restrict__ W3, unsigned short* __restrict__ Wt) {
    int b = blockIdx.x;          // 768 = 3 layers * 256 k-rows
    int L = b >> 8, k = b & 255;
    const float* W = (L == 0) ? W1 : ((L == 1) ? W2 : W3);
    int j = threadIdx.x;
    Wt[L * 65536 + j * 256 + k] = f2bf(W[k * 256 + j]);
}

// ---------------- GEMM: feat = BN(A) @ W  (bf16 MFMA, fp32 acc) ----------------
// block: 256 thr = 4 waves; tile 64 rows x 256 cols; wave w owns cols [64w,64w+64)
// = head w. B fragments read directly from global (L2-resident 128KB) in MFMA
// layout -- no B LDS staging, only 1 barrier. Fused epilogue: el/er + bf16 store.
__launch_bounds__(256, 2)
__global__ void k_gemm(const float* __restrict__ A, const unsigned short* __restrict__ Wt,
                       const float* __restrict__ bnscale, const float* __restrict__ bnshift,
                       int use_bn, const float* __restrict__ al, const float* __restrict__ ar,
                       unsigned short* __restrict__ feat16, float* __restrict__ el,
                       float* __restrict__ er) {
    constexpr int AP = 264;  // A lds pitch in bf16 elems (row start 16B-aligned)
    __shared__ __align__(16) unsigned short Alds[64 * AP];
    const int tid = threadIdx.x;
    const int rowbase = blockIdx.x * 64;

    // stage A: 64 rows x K=256, fp32 -> (BN) -> bf16
    {
        int r = tid >> 6;
        int c4 = tid & 63;
        for (int it = 0; it < 16; it++) {
            int rr = it * 4 + r;
            int gr = rowbase + rr;
            float4 v = make_float4(0.f, 0.f, 0.f, 0.f);
            if (gr < NN) v = *(const float4*)(A + (size_t)gr * 256 + c4 * 4);
            if (use_bn) {
                float4 sc = *(const float4*)(bnscale + c4 * 4);
                float4 sh = *(const float4*)(bnshift + c4 * 4);
                v.x = v.x * sc.x + sh.x;
                v.y = v.y * sc.y + sh.y;
                v.z = v.z * sc.z + sh.z;
                v.w = v.w * sc.w + sh.w;
            }
            ushort4 pv;
            pv.x = f2bf(v.x); pv.y = f2bf(v.y); pv.z = f2bf(v.z); pv.w = f2bf(v.w);
            *(ushort4*)(&Alds[rr * AP + c4 * 4]) = pv;
        }
    }
    __syncthreads();

    f32x4 acc[4][4];
    for (int i = 0; i < 4; i++)
        for (int j = 0; j < 4; j++)
            acc[i][j] = (f32x4){0.f, 0.f, 0.f, 0.f};

    const int lane = tid & 63, w = tid >> 6;
    const int mm = lane & 15, q = lane >> 4;

    const unsigned short* bbase = Wt + ((size_t)(64 * w + mm)) * 256 + q * 8;

#pragma unroll
    for (int kc = 0; kc < 8; kc++) {
        bf16x8 a[4], b[4];
        for (int i = 0; i < 4; i++)
            a[i] = *(const bf16x8*)(&Alds[(16 * i + mm) * AP + kc * 32 + q * 8]);
        for (int j = 0; j < 4; j++)
            b[j] = *(const bf16x8*)(bbase + j * (16 * 256) + kc * 32);
        for (int i = 0; i < 4; i++)
            for (int j = 0; j < 4; j++)
                acc[i][j] = __builtin_amdgcn_mfma_f32_16x16x32_bf16(a[i], b[j], acc[i][j], 0, 0, 0);
    }

    // ---- fused el/er: head w cols are exactly this wave's 64 cols ----
    float alv[4], arv[4];
    for (int j = 0; j < 4; j++) {
        alv[j] = al[w * 64 + 16 * j + mm];
        arv[j] = ar[w * 64 + 16 * j + mm];
    }
    for (int i = 0; i < 4; i++) {
        for (int r = 0; r < 4; r++) {
            int gr = rowbase + 16 * i + q * 4 + r;
            float se = 0.f, sr = 0.f;
            for (int j = 0; j < 4; j++) {
                se += acc[i][j][r] * alv[j];
                sr += acc[i][j][r] * arv[j];
            }
            for (int off = 1; off < 16; off <<= 1) {
                se += __shfl_xor(se, off, 64);
                sr += __shfl_xor(sr, off, 64);
            }
            if (mm == 0 && gr < NN) {
                el[gr * 4 + w] = se;
                er[gr * 4 + w] = sr;
            }
        }
    }

    // ---- feat store as bf16 (C/D layout: col=lane&15, row=(lane>>4)*4+reg) ----
    for (int i = 0; i < 4; i++) {
        for (int j = 0; j < 4; j++) {
            int gc = 64 * w + 16 * j + mm;
            for (int r = 0; r < 4; r++) {
                int gr = rowbase + 16 * i + q * 4 + r;
                if (gr < NN) feat16[(size_t)gr * 256 + gc] = f2bf(acc[i][j][r]);
            }
        }
    }
}

// ---------------- per-dst softmax + weighted aggregation (bf16 gather) ----------------
// one wave per destination node; lane l owns channels [4l, 4l+4); head h = l>>4.
// No-max softmax (scores bounded by BN-normalized inputs). Predicated unroll-8:
// no scalar tail, 8 gathers in flight.
__launch_bounds__(256)
__global__ void k_agg(const unsigned short* __restrict__ feat16, const float* __restrict__ el,
                      const float* __restrict__ er, const int* __restrict__ rowptr,
                      const int* __restrict__ ssrc, const float* __restrict__ resid,
                      const float* __restrict__ bnscale, const float* __restrict__ bnshift,
                      int use_bn, const float* __restrict__ bias, int act,
                      float* __restrict__ out, int final_mean) {
    int n = __builtin_amdgcn_readfirstlane(blockIdx.x * 4 + (threadIdx.x >> 6));
    int l = threadIdx.x & 63;
    int h = l >> 4;
    int beg = rowptr[n], end = rowptr[n + 1];
    float erh = er[n * 4 + h];

    float d = 0.f;
    float4 acc = make_float4(0.f, 0.f, 0.f, 0.f);

    for (int e = beg; e < end; e += 8) {
        int ss[8];
        float cc[8];
        ushort4 ff[8];
#pragma unroll
        for (int j = 0; j < 8; j++) {
            int ee = e + j;
            ss[j] = ssrc[(ee < end) ? ee : beg];
        }
#pragma unroll
        for (int j = 0; j < 8; j++)
            cc[j] = el[ss[j] * 4 + h];
#pragma unroll
        for (int j = 0; j < 8; j++)
            ff[j] = *(const ushort4*)(feat16 + (size_t)ss[j] * 256 + l * 4);
#pragma unroll
        for (int j = 0; j < 8; j++) {
            float sc = cc[j] + erh;
            sc = (sc > 0.f) ? sc : SLOPE_A * sc;
            float wgt = ((e + j) < end) ? __expf(sc) : 0.f;
            d += wgt;
            acc.x += bf2f(ff[j].x) * wgt;
            acc.y += bf2f(ff[j].y) * wgt;
            acc.z += bf2f(ff[j].z) * wgt;
            acc.w += bf2f(ff[j].w) * wgt;
        }
    }

    float invd = 1.f / fmaxf(d, 1e-9f);
    acc.x *= invd; acc.y *= invd; acc.z *= invd; acc.w *= invd;

    // residual (+BN) + bias
    float4 r = *(const float4*)(resid + (size_t)n * 256 + l * 4);
    if (use_bn) {
        float4 sc4 = *(const float4*)(bnscale + l * 4);
        float4 sh4 = *(const float4*)(bnshift + l * 4);
        r.x = r.x * sc4.x + sh4.x;
        r.y = r.y * sc4.y + sh4.y;
        r.z = r.z * sc4.z + sh4.z;
        r.w = r.w * sc4.w + sh4.w;
    }
    float4 bb = *(const float4*)(bias + l * 4);
    acc.x += r.x + bb.x; acc.y += r.y + bb.y;
    acc.z += r.z + bb.z; acc.w += r.w + bb.w;
    if (act) {
        acc.x = (acc.x > 0.f) ? acc.x : SLOPE_R * acc.x;
        acc.y = (acc.y > 0.f) ? acc.y : SLOPE_R * acc.y;
        acc.z = (acc.z > 0.f) ? acc.z : SLOPE_R * acc.z;
        acc.w = (acc.w > 0.f) ? acc.w : SLOPE_R * acc.w;
    }

    if (!final_mean) {
        *(float4*)(out + (size_t)n * 256 + l * 4) = acc;
    } else {
        acc.x += __shfl_xor(acc.x, 16, 64); acc.x += __shfl_xor(acc.x, 32, 64);
        acc.y += __shfl_xor(acc.y, 16, 64); acc.y += __shfl_xor(acc.y, 32, 64);
        acc.z += __shfl_xor(acc.z, 16, 64); acc.z += __shfl_xor(acc.z, 32, 64);
        acc.w += __shfl_xor(acc.w, 16, 64); acc.w += __shfl_xor(acc.w, 32, 64);
        if (l < 16) {
            acc.x *= 0.25f; acc.y *= 0.25f; acc.z *= 0.25f; acc.w *= 0.25f;
            *(float4*)(out + (size_t)n * 64 + l * 4) = acc;
        }
    }
}

// ---------------- BatchNorm stats ----------------
__global__ void k_bnstats(const float* __restrict__ hh, float* __restrict__ sums) {
    int t = threadIdx.x;
    int b = blockIdx.x;
    int r0 = b * 196, r1 = min(r0 + 196, NN);
    float s = 0.f, s2 = 0.f;
    for (int r = r0; r < r1; r++) {
        float v = hh[(size_t)r * 256 + t];
        s += v; s2 += v * v;
    }
    atomicAdd(&sums[t], s);
    atomicAdd(&sums[256 + t], s2);
}

__global__ void k_bnfinal(const float* __restrict__ sums, const float* __restrict__ g,
                          const float* __restrict__ be, float* __restrict__ scale,
                          float* __restrict__ shift) {
    int t = threadIdx.x;
    float mu = sums[t] * (1.f / NN);
    float var = sums[256 + t] * (1.f / NN) - mu * mu;
    float rs = rsqrtf(var + 1e-5f);
    float sc = rs * g[t];
    scale[t] = sc;
    shift[t] = be[t] - mu * sc;
}

// ---------------- launcher ----------------
extern "C" void kernel_launch(void* const* d_in, const int* in_sizes, int n_in,
                              void* d_out, int out_size, void* d_ws, size_t ws_size,
                              hipStream_t stream) {
    const float* x   = (const float*)d_in[0];
    const int* src   = (const int*)d_in[1];
    const int* dst   = (const int*)d_in[2];
    const float* W1  = (const float*)d_in[3];
    const float* al1 = (const float*)d_in[4];
    const float* ar1 = (const float*)d_in[5];
    const float* b1  = (const float*)d_in[6];
    const float* W2  = (const float*)d_in[7];
    const float* al2 = (const float*)d_in[8];
    const float* ar2 = (const float*)d_in[9];
    const float* b2  = (const float*)d_in[10];
    const float* W3  = (const float*)d_in[11];
    const float* al3 = (const float*)d_in[12];
    const float* ar3 = (const float*)d_in[13];
    const float* b3  = (const float*)d_in[14];
    const float* g1  = (const float*)d_in[15];
    const float* be1 = (const float*)d_in[16];
    const float* g2  = (const float*)d_in[17];
    const float* be2 = (const float*)d_in[18];
    float* out = (float*)d_out;

    char* ws = (char*)d_ws;
    size_t off = 0;
    auto alloc = [&](size_t bytes) {
        void* p = ws + off;
        off += (bytes + 255) & ~(size_t)255;
        return p;
    };
    int* rowptr = (int*)alloc((NN + 1) * sizeof(int));
    int* cursor = (int*)alloc(NN * sizeof(int));
    int* cnt    = (int*)alloc(SCB * 256 * sizeof(int));
    int* loc    = (int*)alloc(SCB * 256 * sizeof(int));
    int* bsum   = (int*)alloc(SCB * sizeof(int));
    int* boff   = (int*)alloc(SCB * sizeof(int));
    int* ssrc   = (int*)alloc(NE * sizeof(int));
    unsigned short* feat16 = (unsigned short*)alloc((size_t)NN * 256 * sizeof(unsigned short));
    float* hbuf = (float*)alloc((size_t)NN * 256 * sizeof(float));
    float* el   = (float*)alloc((size_t)NN * 4 * sizeof(float));
    float* er   = (float*)alloc((size_t)NN * 4 * sizeof(float));
    unsigned short* Wt = (unsigned short*)alloc(3 * 65536 * sizeof(unsigned short));
    float* bnsums  = (float*)alloc(512 * sizeof(float));
    float* bnscale = (float*)alloc(256 * sizeof(float));
    float* bnshift = (float*)alloc(256 * sizeof(float));

    // CSR build (graph identical for all layers)
    hipMemsetAsync(cnt, 0, NN * sizeof(int), stream);
    k_hist<<<(NE + 255) / 256, 256, 0, stream>>>(dst, cnt);
    k_scan1<<<SCB, 256, 0, stream>>>(cnt, loc, bsum);
    k_scan2<<<1, 256, 0, stream>>>(bsum, boff, rowptr);
    k_scan3<<<SCB, 256, 0, stream>>>(loc, boff, rowptr, cursor);
    k_scatter<<<(NE + 255) / 256, 256, 0, stream>>>(src, dst, cursor, ssrc);
    k_prepw<<<768, 256, 0, stream>>>(W1, W2, W3, Wt);

    const int GB = (NN + 63) / 64;  // 782
    const int NB = NN / 4;          // 12500

    // ---- layer 1 ----
    k_gemm<<<GB, 256, 0, stream>>>(x, Wt, nullptr, nullptr, 0, al1, ar1, feat16, el, er);
    k_agg<<<NB, 256, 0, stream>>>(feat16, el, er, rowptr, ssrc, x,
                                  nullptr, nullptr, 0, b1, 1, hbuf, 0);
    hipMemsetAsync(bnsums, 0, 512 * sizeof(float), stream);
    k_bnstats<<<256, 256, 0, stream>>>(hbuf, bnsums);
    k_bnfinal<<<1, 256, 0, stream>>>(bnsums, g1, be1, bnscale, bnshift);

    // ---- layer 2 ----
    k_gemm<<<GB, 256, 0, stream>>>(hbuf, Wt + 65536, bnscale, bnshift, 1, al2, ar2, feat16, el, er);
    k_agg<<<NB, 256, 0, stream>>>(feat16, el, er, rowptr, ssrc, hbuf,
                                  bnscale, bnshift, 1, b2, 1, hbuf, 0);
    hipMemsetAsync(bnsums, 0, 512 * sizeof(float), stream);
    k_bnstats<<<256, 256, 0, stream>>>(hbuf, bnsums);
    k_bnfinal<<<1, 256, 0, stream>>>(bnsums, g2, be2, bnscale, bnshift);

    // ---- layer 3 ----
    k_gemm<<<GB, 256, 0, stream>>>(hbuf, Wt + 131072, bnscale, bnshift, 1, al3, ar3, feat16, el, er);
    k_agg<<<NB, 256, 0, stream>>>(feat16, el, er, rowptr, ssrc, hbuf,
                                  bnscale, bnshift, 1, b3, 0, out, 1);
}